// Round 1
// baseline (142.692 us; speedup 1.0000x reference)
//
#include <hip/hip_runtime.h>

#define ALPHA_C      0.5f
#define NUM_CLASSES  100000
#define FEAT_DIM     128
#define BATCH        131072

// ---------------------------------------------------------------------------
// Stage 2: label histogram (counts[label] += 1)
// ---------------------------------------------------------------------------
__global__ void hist_kernel(const int* __restrict__ labels,
                            int* __restrict__ counts, int n) {
    int i = blockIdx.x * blockDim.x + threadIdx.x;
    if (i < n) atomicAdd(&counts[labels[i]], 1);
}

// ---------------------------------------------------------------------------
// Stage 3: per-sample distance + scatter-subtract of scaled deltas.
// One 64-lane wave per sample; lane l handles dims (2l, 2l+1) as float2.
// Reads the ORIGINAL centers (d_in) so output 0 uses pre-update centers
// no matter how the atomic updates to out_centers interleave.
// ---------------------------------------------------------------------------
__global__ __launch_bounds__(256)
void center_kernel(const float* __restrict__ features,
                   const int*   __restrict__ labels,
                   const float* __restrict__ centers,
                   const int*   __restrict__ counts,
                   float* __restrict__ result,
                   float* __restrict__ out_centers) {
    const int wave = threadIdx.x >> 6;      // 4 waves / block
    const int lane = threadIdx.x & 63;
    const int b    = blockIdx.x * 4 + wave; // grid sized exactly: b < BATCH

    const int label = labels[b];

    const float2 f = ((const float2*)(features + (size_t)b     * FEAT_DIM))[lane];
    const float2 c = ((const float2*)(centers  + (size_t)label * FEAT_DIM))[lane];

    const float d0 = f.x - c.x;             // (features - centers_batch)
    const float d1 = f.y - c.y;

    // squared-distance reduction across the wave (64 lanes)
    float ss = d0 * d0 + d1 * d1;
    #pragma unroll
    for (int off = 32; off; off >>= 1) ss += __shfl_xor(ss, off);
    if (lane == 0) result[b] = ss;

    // delta_centers = ALPHA*(c - f)/(1 + count); new = centers - sum(delta)
    // => atomically add  ALPHA*(f - c)/(1 + count)  =  d * inv
    const float inv = ALPHA_C / (1.0f + (float)counts[label]);
    float* dst = out_centers + (size_t)label * FEAT_DIM + 2 * lane;
    unsafeAtomicAdd(dst,     d0 * inv);
    unsafeAtomicAdd(dst + 1, d1 * inv);
}

// ---------------------------------------------------------------------------
extern "C" void kernel_launch(void* const* d_in, const int* in_sizes, int n_in,
                              void* d_out, int out_size, void* d_ws, size_t ws_size,
                              hipStream_t stream) {
    const float* features = (const float*)d_in[0];
    const int*   labels   = (const int*)d_in[1];
    const float* centers  = (const float*)d_in[2];

    float* result      = (float*)d_out;          // [BATCH]
    float* out_centers = result + BATCH;         // [NUM_CLASSES * FEAT_DIM]
    int*   counts      = (int*)d_ws;             // 400 KB scratch

    // zero histogram, copy centers into the output slot (both async, ordered)
    hipMemsetAsync(counts, 0, NUM_CLASSES * sizeof(int), stream);
    hipMemcpyAsync(out_centers, centers,
                   (size_t)NUM_CLASSES * FEAT_DIM * sizeof(float),
                   hipMemcpyDeviceToDevice, stream);

    hist_kernel<<<BATCH / 256, 256, 0, stream>>>(labels, counts, BATCH);

    center_kernel<<<BATCH / 4, 256, 0, stream>>>(features, labels, centers,
                                                 counts, result, out_centers);
}

// Round 2
// 73.453 us; speedup vs baseline: 1.9426x; 1.9426x over previous
//
#include <hip/hip_runtime.h>

#define ALPHA_C    0.5f
#define C_CLASSES  100000
#define D          128
#define BATCH      131072
#define CHUNK      2048
#define NB         ((C_CLASSES + CHUNK - 1) / CHUNK)   // 49 scan blocks

// ---------------------------------------------------------------------------
// K1: label histogram (int atomics — cheap, 131K adds)
// ---------------------------------------------------------------------------
__global__ void hist_kernel(const int* __restrict__ labels,
                            int* __restrict__ counts) {
    int i = blockIdx.x * blockDim.x + threadIdx.x;   // grid == BATCH exactly
    atomicAdd(&counts[labels[i]], 1);
}

// ---------------------------------------------------------------------------
// K2: per-chunk exclusive scan of counts (256 thr × 8 elems = 2048/chunk)
// ---------------------------------------------------------------------------
__global__ __launch_bounds__(256)
void scan1_kernel(const int* __restrict__ counts,
                  int* __restrict__ offsets,
                  int* __restrict__ blockSums) {
    __shared__ int sdata[256];
    const int tid  = threadIdx.x;
    const int base = blockIdx.x * CHUNK + tid * 8;
    int v[8]; int s = 0;
    #pragma unroll
    for (int j = 0; j < 8; ++j) {
        int idx = base + j;
        v[j] = (idx < C_CLASSES) ? counts[idx] : 0;
        s += v[j];
    }
    sdata[tid] = s;
    __syncthreads();
    #pragma unroll
    for (int off = 1; off < 256; off <<= 1) {
        int t = (tid >= off) ? sdata[tid - off] : 0;
        __syncthreads();
        sdata[tid] += t;
        __syncthreads();
    }
    int excl = sdata[tid] - s;                // exclusive prefix for this thread
    #pragma unroll
    for (int j = 0; j < 8; ++j) {
        int idx = base + j;
        if (idx < C_CLASSES) offsets[idx] = excl;
        excl += v[j];
    }
    if (tid == 255) blockSums[blockIdx.x] = sdata[255];
}

// ---------------------------------------------------------------------------
// K3: single-wave scan of the 49 chunk totals
// ---------------------------------------------------------------------------
__global__ void scan2_kernel(const int* __restrict__ blockSums,
                             int* __restrict__ blockOffsets) {
    const int lane = threadIdx.x;             // one wave of 64
    int v = (lane < NB) ? blockSums[lane] : 0;
    int incl = v;
    #pragma unroll
    for (int off = 1; off < 64; off <<= 1) {
        int t = __shfl_up(incl, off);
        if (lane >= off) incl += t;
    }
    blockOffsets[lane] = incl - v;
}

// ---------------------------------------------------------------------------
// K4: add chunk offsets -> final exclusive scan; duplicate into cursor
// ---------------------------------------------------------------------------
__global__ void addoff_kernel(int* __restrict__ offsets,
                              const int* __restrict__ blockOffsets,
                              int* __restrict__ cursor) {
    int i = blockIdx.x * blockDim.x + threadIdx.x;
    if (i < C_CLASSES) {
        int f = offsets[i] + blockOffsets[i / CHUNK];
        offsets[i] = f;
        cursor[i]  = f;
    }
}

// ---------------------------------------------------------------------------
// K5: scatter sample indices into class buckets (131K int atomics)
// ---------------------------------------------------------------------------
__global__ void scatter_kernel(const int* __restrict__ labels,
                               int* __restrict__ cursor,
                               int* __restrict__ order) {
    int b = blockIdx.x * blockDim.x + threadIdx.x;   // grid == BATCH exactly
    int pos = atomicAdd(&cursor[labels[b]], 1);
    order[pos] = b;
}

// ---------------------------------------------------------------------------
// K6: one wave per CLASS. Reads center row once, loops its samples:
//     result[b] = ||f-c||^2 (shfl reduce), acc += (f-c).
//     Writes out = c + ALPHA/(1+n) * acc  — single coalesced row write,
//     zero float atomics. Classes with n=0 are a pure copy.
// ---------------------------------------------------------------------------
__global__ __launch_bounds__(256)
void main_kernel(const float* __restrict__ features,
                 const float* __restrict__ centers,
                 const int*   __restrict__ counts,
                 const int*   __restrict__ offsets,
                 const int*   __restrict__ order,
                 float* __restrict__ result,
                 float* __restrict__ out_centers) {
    const int wave = threadIdx.x >> 6;
    const int lane = threadIdx.x & 63;
    const int c    = blockIdx.x * 4 + wave;
    if (c >= C_CLASSES) return;

    const float2 cv = ((const float2*)(centers + (size_t)c * D))[lane];
    const int n     = counts[c];
    const int start = offsets[c];

    float ax = 0.f, ay = 0.f;
    for (int j = 0; j < n; ++j) {
        const int b = order[start + j];
        const float2 f = ((const float2*)(features + (size_t)b * D))[lane];
        const float dx = f.x - cv.x, dy = f.y - cv.y;
        ax += dx; ay += dy;
        float ss = dx * dx + dy * dy;
        #pragma unroll
        for (int off = 32; off; off >>= 1) ss += __shfl_xor(ss, off);
        if (lane == 0) result[b] = ss;
    }
    const float inv = ALPHA_C / (1.0f + (float)n);
    float2 o;
    o.x = cv.x + ax * inv;
    o.y = cv.y + ay * inv;
    ((float2*)(out_centers + (size_t)c * D))[lane] = o;
}

// ---------------------------------------------------------------------------
extern "C" void kernel_launch(void* const* d_in, const int* in_sizes, int n_in,
                              void* d_out, int out_size, void* d_ws, size_t ws_size,
                              hipStream_t stream) {
    const float* features = (const float*)d_in[0];
    const int*   labels   = (const int*)d_in[1];
    const float* centers  = (const float*)d_in[2];

    float* result      = (float*)d_out;          // [BATCH]
    float* out_centers = result + BATCH;         // [C_CLASSES * D]

    int* ws           = (int*)d_ws;              // ~1.8 MB total scratch
    int* counts       = ws;                      // C
    int* offsets      = ws + C_CLASSES;          // C
    int* cursor       = ws + 2 * C_CLASSES;      // C
    int* blockSums    = ws + 3 * C_CLASSES;      // 64
    int* blockOffsets = blockSums + 64;          // 64
    int* order        = blockOffsets + 64;       // BATCH

    hipMemsetAsync(counts, 0, C_CLASSES * sizeof(int), stream);

    hist_kernel   <<<BATCH / 256, 256, 0, stream>>>(labels, counts);
    scan1_kernel  <<<NB,          256, 0, stream>>>(counts, offsets, blockSums);
    scan2_kernel  <<<1,            64, 0, stream>>>(blockSums, blockOffsets);
    addoff_kernel <<<(C_CLASSES + 255) / 256, 256, 0, stream>>>(offsets, blockOffsets, cursor);
    scatter_kernel<<<BATCH / 256, 256, 0, stream>>>(labels, cursor, order);

    main_kernel   <<<(C_CLASSES + 3) / 4, 256, 0, stream>>>(
        features, centers, counts, offsets, order, result, out_centers);
}

// Round 3
// 66.607 us; speedup vs baseline: 2.1423x; 1.1028x over previous
//
#include <hip/hip_runtime.h>

#define ALPHA_C    0.5f
#define C_CLASSES  100000
#define D          128
#define BATCH      131072
#define CHUNK      2048
#define NB         ((C_CLASSES + CHUNK - 1) / CHUNK)   // 49 scan blocks
#define G          4                                   // classes per wave

// ---------------------------------------------------------------------------
// K1: label histogram (int atomics — cheap, 131K adds)
// ---------------------------------------------------------------------------
__global__ void hist_kernel(const int* __restrict__ labels,
                            int* __restrict__ counts) {
    int i = blockIdx.x * blockDim.x + threadIdx.x;   // grid == BATCH exactly
    atomicAdd(&counts[labels[i]], 1);
}

// ---------------------------------------------------------------------------
// K2: per-chunk exclusive scan of counts; writes {chunk_excl, count} pairs
// ---------------------------------------------------------------------------
__global__ __launch_bounds__(256)
void scan1_kernel(const int* __restrict__ counts,
                  int2* __restrict__ co,
                  int* __restrict__ blockSums) {
    __shared__ int sdata[256];
    const int tid  = threadIdx.x;
    const int base = blockIdx.x * CHUNK + tid * 8;
    int v[8]; int s = 0;
    #pragma unroll
    for (int j = 0; j < 8; ++j) {
        int idx = base + j;
        v[j] = (idx < C_CLASSES) ? counts[idx] : 0;
        s += v[j];
    }
    sdata[tid] = s;
    __syncthreads();
    #pragma unroll
    for (int off = 1; off < 256; off <<= 1) {
        int t = (tid >= off) ? sdata[tid - off] : 0;
        __syncthreads();
        sdata[tid] += t;
        __syncthreads();
    }
    int excl = sdata[tid] - s;                // exclusive prefix within chunk
    #pragma unroll
    for (int j = 0; j < 8; ++j) {
        int idx = base + j;
        if (idx < C_CLASSES) co[idx] = make_int2(excl, v[j]);
        excl += v[j];
    }
    if (tid == 255) blockSums[blockIdx.x] = sdata[255];
}

// ---------------------------------------------------------------------------
// K3: single-wave scan of the 49 chunk totals
// ---------------------------------------------------------------------------
__global__ void scan2_kernel(const int* __restrict__ blockSums,
                             int* __restrict__ blockOffsets) {
    const int lane = threadIdx.x;             // one wave of 64
    int v = (lane < NB) ? blockSums[lane] : 0;
    int incl = v;
    #pragma unroll
    for (int off = 1; off < 64; off <<= 1) {
        int t = __shfl_up(incl, off);
        if (lane >= off) incl += t;
    }
    blockOffsets[lane] = incl - v;
}

// ---------------------------------------------------------------------------
// K4: finalize offsets in co.x; seed scatter cursor
// ---------------------------------------------------------------------------
__global__ void addoff_kernel(int2* __restrict__ co,
                              const int* __restrict__ blockOffsets,
                              int* __restrict__ cursor) {
    int i = blockIdx.x * blockDim.x + threadIdx.x;
    if (i < C_CLASSES) {
        int f = co[i].x + blockOffsets[i / CHUNK];
        co[i].x = f;
        cursor[i] = f;
    }
}

// ---------------------------------------------------------------------------
// K5: scatter sample indices into class buckets (131K int atomics)
// ---------------------------------------------------------------------------
__global__ void scatter_kernel(const int* __restrict__ labels,
                               int* __restrict__ cursor,
                               int* __restrict__ order) {
    int b = blockIdx.x * blockDim.x + threadIdx.x;   // grid == BATCH exactly
    int pos = atomicAdd(&cursor[labels[b]], 1);
    order[pos] = b;
}

// ---------------------------------------------------------------------------
// K6: one wave per G=4 CONSECUTIVE classes.
//  - their CSR ranges are contiguous -> ONE coalesced order[] load for all
//    samples of all 4 classes (kills one dependent-load hop)
//  - 4 center rows = one contiguous 2KB read
//  - per-sample feature loads independent (unroll 4 -> >=4 loads in flight)
//  - class membership by wave-uniform position compares (branch-free)
// ---------------------------------------------------------------------------
__global__ __launch_bounds__(256)
void main_kernel(const float* __restrict__ features,
                 const float* __restrict__ centers,
                 const int2*  __restrict__ co,
                 const int*   __restrict__ order,
                 float* __restrict__ result,
                 float* __restrict__ out_centers) {
    const int wave = threadIdx.x >> 6;
    const int lane = threadIdx.x & 63;
    const int c0   = (blockIdx.x * 4 + wave) * G;    // grid exact: c0 < C

    const int2 m0 = co[c0];
    const int2 m1 = co[c0 + 1];
    const int2 m2 = co[c0 + 2];
    const int2 m3 = co[c0 + 3];
    const int start = m0.x;
    const int b1 = m1.x, b2 = m2.x, b3 = m3.x;       // class boundaries
    const int end = m3.x + m3.y;

    const float2* cp = (const float2*)(centers + (size_t)c0 * D);
    const float2 cv0 = cp[lane];
    const float2 cv1 = cp[lane + 64];
    const float2 cv2 = cp[lane + 128];
    const float2 cv3 = cp[lane + 192];

    float ax0 = 0.f, ay0 = 0.f, ax1 = 0.f, ay1 = 0.f;
    float ax2 = 0.f, ay2 = 0.f, ax3 = 0.f, ay3 = 0.f;

    for (int s = start; s < end; s += 64) {          // almost always 1 iter
        const int m = min(64, end - s);
        const int ov = (s + lane < end) ? order[s + lane] : 0;
        #pragma unroll 4
        for (int j = 0; j < m; ++j) {
            const int b = __shfl(ov, j);
            const float2 f = ((const float2*)(features + (size_t)b * D))[lane];
            const int p = s + j;                      // wave-uniform
            const float cx = p < b1 ? cv0.x : p < b2 ? cv1.x : p < b3 ? cv2.x : cv3.x;
            const float cy = p < b1 ? cv0.y : p < b2 ? cv1.y : p < b3 ? cv2.y : cv3.y;
            const float dx = f.x - cx, dy = f.y - cy;
            ax0 += (p < b1) ? dx : 0.f;              ay0 += (p < b1) ? dy : 0.f;
            ax1 += (p >= b1 && p < b2) ? dx : 0.f;   ay1 += (p >= b1 && p < b2) ? dy : 0.f;
            ax2 += (p >= b2 && p < b3) ? dx : 0.f;   ay2 += (p >= b2 && p < b3) ? dy : 0.f;
            ax3 += (p >= b3) ? dx : 0.f;             ay3 += (p >= b3) ? dy : 0.f;
            float ss = dx * dx + dy * dy;
            #pragma unroll
            for (int off = 32; off; off >>= 1) ss += __shfl_xor(ss, off);
            if (lane == 0) result[b] = ss;
        }
    }

    const float i0 = ALPHA_C / (1.0f + (float)m0.y);
    const float i1 = ALPHA_C / (1.0f + (float)m1.y);
    const float i2 = ALPHA_C / (1.0f + (float)m2.y);
    const float i3 = ALPHA_C / (1.0f + (float)m3.y);
    float2* op = (float2*)(out_centers + (size_t)c0 * D);
    float2 o;
    o.x = cv0.x + ax0 * i0; o.y = cv0.y + ay0 * i0; op[lane]       = o;
    o.x = cv1.x + ax1 * i1; o.y = cv1.y + ay1 * i1; op[lane + 64]  = o;
    o.x = cv2.x + ax2 * i2; o.y = cv2.y + ay2 * i2; op[lane + 128] = o;
    o.x = cv3.x + ax3 * i3; o.y = cv3.y + ay3 * i3; op[lane + 192] = o;
}

// ---------------------------------------------------------------------------
extern "C" void kernel_launch(void* const* d_in, const int* in_sizes, int n_in,
                              void* d_out, int out_size, void* d_ws, size_t ws_size,
                              hipStream_t stream) {
    const float* features = (const float*)d_in[0];
    const int*   labels   = (const int*)d_in[1];
    const float* centers  = (const float*)d_in[2];

    float* result      = (float*)d_out;          // [BATCH]
    float* out_centers = result + BATCH;         // [C_CLASSES * D]

    int*  ws           = (int*)d_ws;             // ~2.1 MB total scratch
    int*  counts       = ws;                     // C
    int2* co           = (int2*)(ws + C_CLASSES);        // 2C ints
    int*  cursor       = ws + 3 * C_CLASSES;     // C
    int*  blockSums    = ws + 4 * C_CLASSES;     // 64
    int*  blockOffsets = blockSums + 64;         // 64
    int*  order        = blockOffsets + 64;      // BATCH

    hipMemsetAsync(counts, 0, C_CLASSES * sizeof(int), stream);

    hist_kernel   <<<BATCH / 256, 256, 0, stream>>>(labels, counts);
    scan1_kernel  <<<NB,          256, 0, stream>>>(counts, co, blockSums);
    scan2_kernel  <<<1,            64, 0, stream>>>(blockSums, blockOffsets);
    addoff_kernel <<<(C_CLASSES + 255) / 256, 256, 0, stream>>>(co, blockOffsets, cursor);
    scatter_kernel<<<BATCH / 256, 256, 0, stream>>>(labels, cursor, order);

    main_kernel   <<<C_CLASSES / (4 * G), 256, 0, stream>>>(
        features, centers, co, order, result, out_centers);
}

// Round 4
// 64.384 us; speedup vs baseline: 2.2163x; 1.0345x over previous
//
#include <hip/hip_runtime.h>

#define ALPHA_C    0.5f
#define C_CLASSES  100000
#define D          128
#define BATCH      131072
#define CHUNK      2048
#define NB         ((C_CLASSES + CHUNK - 1) / CHUNK)   // 49 scan blocks
#define G          4                                   // classes per wave

// ---------------------------------------------------------------------------
// K1: label histogram (int atomics — cheap, 131K adds)
// ---------------------------------------------------------------------------
__global__ void hist_kernel(const int* __restrict__ labels,
                            int* __restrict__ counts) {
    int i = blockIdx.x * blockDim.x + threadIdx.x;   // grid == BATCH exactly
    atomicAdd(&counts[labels[i]], 1);
}

// ---------------------------------------------------------------------------
// K2: per-chunk exclusive scan of counts; writes {chunk_excl, count} pairs
// ---------------------------------------------------------------------------
__global__ __launch_bounds__(256)
void scan1_kernel(const int* __restrict__ counts,
                  int2* __restrict__ co,
                  int* __restrict__ blockSums) {
    __shared__ int sdata[256];
    const int tid  = threadIdx.x;
    const int base = blockIdx.x * CHUNK + tid * 8;
    int v[8]; int s = 0;
    #pragma unroll
    for (int j = 0; j < 8; ++j) {
        int idx = base + j;
        v[j] = (idx < C_CLASSES) ? counts[idx] : 0;
        s += v[j];
    }
    sdata[tid] = s;
    __syncthreads();
    #pragma unroll
    for (int off = 1; off < 256; off <<= 1) {
        int t = (tid >= off) ? sdata[tid - off] : 0;
        __syncthreads();
        sdata[tid] += t;
        __syncthreads();
    }
    int excl = sdata[tid] - s;                // exclusive prefix within chunk
    #pragma unroll
    for (int j = 0; j < 8; ++j) {
        int idx = base + j;
        if (idx < C_CLASSES) co[idx] = make_int2(excl, v[j]);
        excl += v[j];
    }
    if (tid == 255) blockSums[blockIdx.x] = sdata[255];
}

// ---------------------------------------------------------------------------
// K3: single-wave scan of the 49 chunk totals
// ---------------------------------------------------------------------------
__global__ void scan2_kernel(const int* __restrict__ blockSums,
                             int* __restrict__ blockOffsets) {
    const int lane = threadIdx.x;             // one wave of 64
    int v = (lane < NB) ? blockSums[lane] : 0;
    int incl = v;
    #pragma unroll
    for (int off = 1; off < 64; off <<= 1) {
        int t = __shfl_up(incl, off);
        if (lane >= off) incl += t;
    }
    blockOffsets[lane] = incl - v;
}

// ---------------------------------------------------------------------------
// K4: finalize offsets in co.x; seed scatter cursor
// ---------------------------------------------------------------------------
__global__ void addoff_kernel(int2* __restrict__ co,
                              const int* __restrict__ blockOffsets,
                              int* __restrict__ cursor) {
    int i = blockIdx.x * blockDim.x + threadIdx.x;
    if (i < C_CLASSES) {
        int f = co[i].x + blockOffsets[i / CHUNK];
        co[i].x = f;
        cursor[i] = f;
    }
}

// ---------------------------------------------------------------------------
// K5: scatter sample indices into class buckets (131K int atomics)
// ---------------------------------------------------------------------------
__global__ void scatter_kernel(const int* __restrict__ labels,
                               int* __restrict__ cursor,
                               int* __restrict__ order) {
    int b = blockIdx.x * blockDim.x + threadIdx.x;   // grid == BATCH exactly
    int pos = atomicAdd(&cursor[labels[b]], 1);
    order[pos] = b;
}

// ---------------------------------------------------------------------------
// K6: one wave per G=4 consecutive classes, software-pipelined 8-deep.
//  - CSR metadata readfirstlane'd -> SGPR -> order[] loads are wave-uniform
//  - all 8 order loads, then all 8 feature loads issued before ANY use:
//    8 independent HBM loads in flight per wave (latency amortized 8x)
//  - 8 shuffle-reduce chains are independent -> scheduler interleaves
//  - tail via clamped index + zeroed contribution (no divergence, no dupes)
// ---------------------------------------------------------------------------
__global__ __launch_bounds__(256)
void main_kernel(const float* __restrict__ features,
                 const float* __restrict__ centers,
                 const int2*  __restrict__ co,
                 const int*   __restrict__ order,
                 float* __restrict__ result,
                 float* __restrict__ out_centers) {
    const int wave = threadIdx.x >> 6;
    const int lane = threadIdx.x & 63;
    const int c0   = (blockIdx.x * 4 + wave) * G;    // grid exact: c0 < C

    // 4x int2 metadata as two int4 loads, then to SGPRs (wave-uniform)
    const int4 mA = ((const int4*)(co + c0))[0];
    const int4 mB = ((const int4*)(co + c0))[1];
    const int start = __builtin_amdgcn_readfirstlane(mA.x);
    const int n0    = __builtin_amdgcn_readfirstlane(mA.y);
    const int b1    = __builtin_amdgcn_readfirstlane(mA.z);
    const int n1    = __builtin_amdgcn_readfirstlane(mA.w);
    const int b2    = __builtin_amdgcn_readfirstlane(mB.x);
    const int n2    = __builtin_amdgcn_readfirstlane(mB.y);
    const int b3    = __builtin_amdgcn_readfirstlane(mB.z);
    const int n3    = __builtin_amdgcn_readfirstlane(mB.w);
    const int end   = b3 + n3;

    const float2* cp = (const float2*)(centers + (size_t)c0 * D);
    const float2 cv0 = cp[lane];
    const float2 cv1 = cp[lane + 64];
    const float2 cv2 = cp[lane + 128];
    const float2 cv3 = cp[lane + 192];

    float ax0 = 0.f, ay0 = 0.f, ax1 = 0.f, ay1 = 0.f;
    float ax2 = 0.f, ay2 = 0.f, ax3 = 0.f, ay3 = 0.f;

    for (int p0 = start; p0 < end; p0 += 8) {
        // batch of 8 sample indices (uniform addresses, clamped tail)
        int bi[8];
        #pragma unroll
        for (int u = 0; u < 8; ++u)
            bi[u] = order[min(p0 + u, end - 1)];
        // 8 independent feature-row loads in flight
        float2 f[8];
        #pragma unroll
        for (int u = 0; u < 8; ++u)
            f[u] = ((const float2*)(features + (size_t)bi[u] * D))[lane];
        // consume
        #pragma unroll
        for (int u = 0; u < 8; ++u) {
            const int p = p0 + u;                      // wave-uniform
            const float cx = p < b1 ? cv0.x : p < b2 ? cv1.x : p < b3 ? cv2.x : cv3.x;
            const float cy = p < b1 ? cv0.y : p < b2 ? cv1.y : p < b3 ? cv2.y : cv3.y;
            float dx = f[u].x - cx, dy = f[u].y - cy;
            if (p >= end) { dx = 0.f; dy = 0.f; }      // kill tail contribution
            ax0 += (p < b1) ? dx : 0.f;              ay0 += (p < b1) ? dy : 0.f;
            ax1 += (p >= b1 && p < b2) ? dx : 0.f;   ay1 += (p >= b1 && p < b2) ? dy : 0.f;
            ax2 += (p >= b2 && p < b3) ? dx : 0.f;   ay2 += (p >= b2 && p < b3) ? dy : 0.f;
            ax3 += (p >= b3) ? dx : 0.f;             ay3 += (p >= b3) ? dy : 0.f;
            float ss = dx * dx + dy * dy;
            #pragma unroll
            for (int off = 32; off; off >>= 1) ss += __shfl_xor(ss, off);
            if (p < end && lane == 0) result[bi[u]] = ss;
        }
    }

    const float i0 = ALPHA_C / (1.0f + (float)n0);
    const float i1 = ALPHA_C / (1.0f + (float)n1);
    const float i2 = ALPHA_C / (1.0f + (float)n2);
    const float i3 = ALPHA_C / (1.0f + (float)n3);
    float2* op = (float2*)(out_centers + (size_t)c0 * D);
    float2 o;
    o.x = cv0.x + ax0 * i0; o.y = cv0.y + ay0 * i0; op[lane]       = o;
    o.x = cv1.x + ax1 * i1; o.y = cv1.y + ay1 * i1; op[lane + 64]  = o;
    o.x = cv2.x + ax2 * i2; o.y = cv2.y + ay2 * i2; op[lane + 128] = o;
    o.x = cv3.x + ax3 * i3; o.y = cv3.y + ay3 * i3; op[lane + 192] = o;
}

// ---------------------------------------------------------------------------
extern "C" void kernel_launch(void* const* d_in, const int* in_sizes, int n_in,
                              void* d_out, int out_size, void* d_ws, size_t ws_size,
                              hipStream_t stream) {
    const float* features = (const float*)d_in[0];
    const int*   labels   = (const int*)d_in[1];
    const float* centers  = (const float*)d_in[2];

    float* result      = (float*)d_out;          // [BATCH]
    float* out_centers = result + BATCH;         // [C_CLASSES * D]

    int*  ws           = (int*)d_ws;             // ~2.1 MB total scratch
    int*  counts       = ws;                     // C
    int2* co           = (int2*)(ws + C_CLASSES);        // 2C ints
    int*  cursor       = ws + 3 * C_CLASSES;     // C
    int*  blockSums    = ws + 4 * C_CLASSES;     // 64
    int*  blockOffsets = blockSums + 64;         // 64
    int*  order        = blockOffsets + 64;      // BATCH

    hipMemsetAsync(counts, 0, C_CLASSES * sizeof(int), stream);

    hist_kernel   <<<BATCH / 256, 256, 0, stream>>>(labels, counts);
    scan1_kernel  <<<NB,          256, 0, stream>>>(counts, co, blockSums);
    scan2_kernel  <<<1,            64, 0, stream>>>(blockSums, blockOffsets);
    addoff_kernel <<<(C_CLASSES + 255) / 256, 256, 0, stream>>>(co, blockOffsets, cursor);
    scatter_kernel<<<BATCH / 256, 256, 0, stream>>>(labels, cursor, order);

    main_kernel   <<<C_CLASSES / (4 * G), 256, 0, stream>>>(
        features, centers, co, order, result, out_centers);
}

// Round 5
// 64.222 us; speedup vs baseline: 2.2219x; 1.0025x over previous
//
#include <hip/hip_runtime.h>

#define ALPHA_C    0.5f
#define C_CLASSES  100000
#define D          128
#define BATCH      131072
#define CHUNK      2048
#define NB         ((C_CLASSES + CHUNK - 1) / CHUNK)   // 49 scan blocks
#define G          4                                   // classes per wave

// ---------------------------------------------------------------------------
// K1: label histogram (int atomics — cheap, 131K adds)
// ---------------------------------------------------------------------------
__global__ void hist_kernel(const int* __restrict__ labels,
                            int* __restrict__ counts) {
    int i = blockIdx.x * blockDim.x + threadIdx.x;   // grid == BATCH exactly
    atomicAdd(&counts[labels[i]], 1);
}

// ---------------------------------------------------------------------------
// K2: per-chunk exclusive scan of counts; writes {chunk_excl, count} pairs
// ---------------------------------------------------------------------------
__global__ __launch_bounds__(256)
void scan1_kernel(const int* __restrict__ counts,
                  int2* __restrict__ co,
                  int* __restrict__ blockSums) {
    __shared__ int sdata[256];
    const int tid  = threadIdx.x;
    const int base = blockIdx.x * CHUNK + tid * 8;
    int v[8]; int s = 0;
    #pragma unroll
    for (int j = 0; j < 8; ++j) {
        int idx = base + j;
        v[j] = (idx < C_CLASSES) ? counts[idx] : 0;
        s += v[j];
    }
    sdata[tid] = s;
    __syncthreads();
    #pragma unroll
    for (int off = 1; off < 256; off <<= 1) {
        int t = (tid >= off) ? sdata[tid - off] : 0;
        __syncthreads();
        sdata[tid] += t;
        __syncthreads();
    }
    int excl = sdata[tid] - s;                // exclusive prefix within chunk
    #pragma unroll
    for (int j = 0; j < 8; ++j) {
        int idx = base + j;
        if (idx < C_CLASSES) co[idx] = make_int2(excl, v[j]);
        excl += v[j];
    }
    if (tid == 255) blockSums[blockIdx.x] = sdata[255];
}

// ---------------------------------------------------------------------------
// K3: single-wave scan of the 49 chunk totals
// ---------------------------------------------------------------------------
__global__ void scan2_kernel(const int* __restrict__ blockSums,
                             int* __restrict__ blockOffsets) {
    const int lane = threadIdx.x;             // one wave of 64
    int v = (lane < NB) ? blockSums[lane] : 0;
    int incl = v;
    #pragma unroll
    for (int off = 1; off < 64; off <<= 1) {
        int t = __shfl_up(incl, off);
        if (lane >= off) incl += t;
    }
    blockOffsets[lane] = incl - v;
}

// ---------------------------------------------------------------------------
// K4: finalize offsets in co.x; seed scatter cursor
// ---------------------------------------------------------------------------
__global__ void addoff_kernel(int2* __restrict__ co,
                              const int* __restrict__ blockOffsets,
                              int* __restrict__ cursor) {
    int i = blockIdx.x * blockDim.x + threadIdx.x;
    if (i < C_CLASSES) {
        int f = co[i].x + blockOffsets[i / CHUNK];
        co[i].x = f;
        cursor[i] = f;
    }
}

// ---------------------------------------------------------------------------
// K5: scatter sample indices into class buckets (131K int atomics)
// ---------------------------------------------------------------------------
__global__ void scatter_kernel(const int* __restrict__ labels,
                               int* __restrict__ cursor,
                               int* __restrict__ order) {
    int b = blockIdx.x * blockDim.x + threadIdx.x;   // grid == BATCH exactly
    int pos = atomicAdd(&cursor[labels[b]], 1);
    order[pos] = b;
}

// ---------------------------------------------------------------------------
// K6: one wave per G=4 consecutive classes, software-pipelined 8-deep.
//  R5 fix: R4's batching was silently serialized by regalloc (VGPR=28 can't
//  hold f[8]+bi[8]). Now: sched_barrier(0) between load batch and consume
//  forces all 8 order-loads + 8 feature-row loads to ISSUE before any use,
//  and __launch_bounds__(256,2) gives regalloc a 256-VGPR budget to keep
//  them live. 8x 512B rows in flight per wave => latency amortized.
// ---------------------------------------------------------------------------
__global__ __launch_bounds__(256, 2)
void main_kernel(const float* __restrict__ features,
                 const float* __restrict__ centers,
                 const int2*  __restrict__ co,
                 const int*   __restrict__ order,
                 float* __restrict__ result,
                 float* __restrict__ out_centers) {
    const int wave = threadIdx.x >> 6;
    const int lane = threadIdx.x & 63;
    const int c0   = (blockIdx.x * 4 + wave) * G;    // grid exact: c0 < C

    // 4x int2 metadata as two int4 loads, then to SGPRs (wave-uniform)
    const int4 mA = ((const int4*)(co + c0))[0];
    const int4 mB = ((const int4*)(co + c0))[1];
    const int start = __builtin_amdgcn_readfirstlane(mA.x);
    const int n0    = __builtin_amdgcn_readfirstlane(mA.y);
    const int b1    = __builtin_amdgcn_readfirstlane(mA.z);
    const int n1    = __builtin_amdgcn_readfirstlane(mA.w);
    const int b2    = __builtin_amdgcn_readfirstlane(mB.x);
    const int n2    = __builtin_amdgcn_readfirstlane(mB.y);
    const int b3    = __builtin_amdgcn_readfirstlane(mB.z);
    const int n3    = __builtin_amdgcn_readfirstlane(mB.w);
    const int end   = b3 + n3;

    const float2* cp = (const float2*)(centers + (size_t)c0 * D);
    const float2 cv0 = cp[lane];
    const float2 cv1 = cp[lane + 64];
    const float2 cv2 = cp[lane + 128];
    const float2 cv3 = cp[lane + 192];

    float ax0 = 0.f, ay0 = 0.f, ax1 = 0.f, ay1 = 0.f;
    float ax2 = 0.f, ay2 = 0.f, ax3 = 0.f, ay3 = 0.f;

    for (int p0 = start; p0 < end; p0 += 8) {
        // batch of 8 sample indices (uniform/scalar loads, clamped tail)
        int bi[8];
        #pragma unroll
        for (int u = 0; u < 8; ++u)
            bi[u] = order[min(p0 + u, end - 1)];
        // 8 independent 512B feature-row loads — must all issue before use
        float2 f[8];
        #pragma unroll
        for (int u = 0; u < 8; ++u)
            f[u] = ((const float2*)(features + (size_t)bi[u] * D))[lane];
        __builtin_amdgcn_sched_barrier(0);   // loads may not sink below here
        // consume
        #pragma unroll
        for (int u = 0; u < 8; ++u) {
            const int p = p0 + u;                      // wave-uniform
            const float cx = p < b1 ? cv0.x : p < b2 ? cv1.x : p < b3 ? cv2.x : cv3.x;
            const float cy = p < b1 ? cv0.y : p < b2 ? cv1.y : p < b3 ? cv2.y : cv3.y;
            float dx = f[u].x - cx, dy = f[u].y - cy;
            if (p >= end) { dx = 0.f; dy = 0.f; }      // kill tail contribution
            ax0 += (p < b1) ? dx : 0.f;              ay0 += (p < b1) ? dy : 0.f;
            ax1 += (p >= b1 && p < b2) ? dx : 0.f;   ay1 += (p >= b1 && p < b2) ? dy : 0.f;
            ax2 += (p >= b2 && p < b3) ? dx : 0.f;   ay2 += (p >= b2 && p < b3) ? dy : 0.f;
            ax3 += (p >= b3) ? dx : 0.f;             ay3 += (p >= b3) ? dy : 0.f;
            float ss = dx * dx + dy * dy;
            #pragma unroll
            for (int off = 32; off; off >>= 1) ss += __shfl_xor(ss, off);
            if (p < end && lane == 0) result[bi[u]] = ss;
        }
    }

    const float i0 = ALPHA_C / (1.0f + (float)n0);
    const float i1 = ALPHA_C / (1.0f + (float)n1);
    const float i2 = ALPHA_C / (1.0f + (float)n2);
    const float i3 = ALPHA_C / (1.0f + (float)n3);
    float2* op = (float2*)(out_centers + (size_t)c0 * D);
    float2 o;
    o.x = cv0.x + ax0 * i0; o.y = cv0.y + ay0 * i0; op[lane]       = o;
    o.x = cv1.x + ax1 * i1; o.y = cv1.y + ay1 * i1; op[lane + 64]  = o;
    o.x = cv2.x + ax2 * i2; o.y = cv2.y + ay2 * i2; op[lane + 128] = o;
    o.x = cv3.x + ax3 * i3; o.y = cv3.y + ay3 * i3; op[lane + 192] = o;
}

// ---------------------------------------------------------------------------
extern "C" void kernel_launch(void* const* d_in, const int* in_sizes, int n_in,
                              void* d_out, int out_size, void* d_ws, size_t ws_size,
                              hipStream_t stream) {
    const float* features = (const float*)d_in[0];
    const int*   labels   = (const int*)d_in[1];
    const float* centers  = (const float*)d_in[2];

    float* result      = (float*)d_out;          // [BATCH]
    float* out_centers = result + BATCH;         // [C_CLASSES * D]

    int*  ws           = (int*)d_ws;             // ~2.1 MB total scratch
    int*  counts       = ws;                     // C
    int2* co           = (int2*)(ws + C_CLASSES);        // 2C ints
    int*  cursor       = ws + 3 * C_CLASSES;     // C
    int*  blockSums    = ws + 4 * C_CLASSES;     // 64
    int*  blockOffsets = blockSums + 64;         // 64
    int*  order        = blockOffsets + 64;      // BATCH

    hipMemsetAsync(counts, 0, C_CLASSES * sizeof(int), stream);

    hist_kernel   <<<BATCH / 256, 256, 0, stream>>>(labels, counts);
    scan1_kernel  <<<NB,          256, 0, stream>>>(counts, co, blockSums);
    scan2_kernel  <<<1,            64, 0, stream>>>(blockSums, blockOffsets);
    addoff_kernel <<<(C_CLASSES + 255) / 256, 256, 0, stream>>>(co, blockOffsets, cursor);
    scatter_kernel<<<BATCH / 256, 256, 0, stream>>>(labels, cursor, order);

    main_kernel   <<<C_CLASSES / (4 * G), 256, 0, stream>>>(
        features, centers, co, order, result, out_centers);
}

// Round 7
// 62.314 us; speedup vs baseline: 2.2899x; 1.0306x over previous
//
#include <hip/hip_runtime.h>

#define ALPHA_C    0.5f
#define C_CLASSES  100000
#define D          128
#define BATCH      131072
#define CHUNK      2048
#define NB         ((C_CLASSES + CHUNK - 1) / CHUNK)   // 49 scan blocks
#define G          4                                   // classes per wave

// ---------------------------------------------------------------------------
// DPP wave-sum helper: x + dpp_shifted(x). VALU-speed (no LDS pipe).
// CTRL/RMASK are template params -> true immediates (builtin requires them).
// Sequence row_shr 1,2,4,8 then bcast15(rows1,3), bcast31(rows2,3)
// leaves the full 64-lane sum in lane 63.  (GPUOpen cross-lane idiom.)
// ---------------------------------------------------------------------------
template<int CTRL, int RMASK>
__device__ __forceinline__ float dpp_add(float x) {
    int v = __builtin_amdgcn_update_dpp(0, __float_as_int(x), CTRL, RMASK, 0xF, true);
    return x + __int_as_float(v);
}
__device__ __forceinline__ float wave_sum63(float ss) {
    ss = dpp_add<0x111, 0xF>(ss);   // row_shr:1
    ss = dpp_add<0x112, 0xF>(ss);   // row_shr:2
    ss = dpp_add<0x114, 0xF>(ss);   // row_shr:4
    ss = dpp_add<0x118, 0xF>(ss);   // row_shr:8  -> lane15 of each row = row sum
    ss = dpp_add<0x142, 0xA>(ss);   // bcast15 -> rows 1,3
    ss = dpp_add<0x143, 0xC>(ss);   // bcast31 -> rows 2,3; lane63 = total
    return ss;
}

// ---------------------------------------------------------------------------
// K1: label histogram
// ---------------------------------------------------------------------------
__global__ void hist_kernel(const int* __restrict__ labels,
                            int* __restrict__ counts) {
    int i = blockIdx.x * blockDim.x + threadIdx.x;   // grid == BATCH exactly
    atomicAdd(&counts[labels[i]], 1);
}

// ---------------------------------------------------------------------------
// K2: per-chunk exclusive scan of counts; writes {chunk_excl, count} pairs
// ---------------------------------------------------------------------------
__global__ __launch_bounds__(256)
void scan1_kernel(const int* __restrict__ counts,
                  int2* __restrict__ co,
                  int* __restrict__ blockSums) {
    __shared__ int sdata[256];
    const int tid  = threadIdx.x;
    const int base = blockIdx.x * CHUNK + tid * 8;
    int v[8]; int s = 0;
    #pragma unroll
    for (int j = 0; j < 8; ++j) {
        int idx = base + j;
        v[j] = (idx < C_CLASSES) ? counts[idx] : 0;
        s += v[j];
    }
    sdata[tid] = s;
    __syncthreads();
    #pragma unroll
    for (int off = 1; off < 256; off <<= 1) {
        int t = (tid >= off) ? sdata[tid - off] : 0;
        __syncthreads();
        sdata[tid] += t;
        __syncthreads();
    }
    int excl = sdata[tid] - s;
    #pragma unroll
    for (int j = 0; j < 8; ++j) {
        int idx = base + j;
        if (idx < C_CLASSES) co[idx] = make_int2(excl, v[j]);
        excl += v[j];
    }
    if (tid == 255) blockSums[blockIdx.x] = sdata[255];
}

// ---------------------------------------------------------------------------
// K3: single-wave scan of the 49 chunk totals
// ---------------------------------------------------------------------------
__global__ void scan2_kernel(const int* __restrict__ blockSums,
                             int* __restrict__ blockOffsets) {
    const int lane = threadIdx.x;
    int v = (lane < NB) ? blockSums[lane] : 0;
    int incl = v;
    #pragma unroll
    for (int off = 1; off < 64; off <<= 1) {
        int t = __shfl_up(incl, off);
        if (lane >= off) incl += t;
    }
    blockOffsets[lane] = incl - v;
}

// ---------------------------------------------------------------------------
// K4: finalize offsets in co.x; seed scatter cursor
// ---------------------------------------------------------------------------
__global__ void addoff_kernel(int2* __restrict__ co,
                              const int* __restrict__ blockOffsets,
                              int* __restrict__ cursor) {
    int i = blockIdx.x * blockDim.x + threadIdx.x;
    if (i < C_CLASSES) {
        int f = co[i].x + blockOffsets[i / CHUNK];
        co[i].x = f;
        cursor[i] = f;
    }
}

// ---------------------------------------------------------------------------
// K5: scatter sample indices into class buckets
// ---------------------------------------------------------------------------
__global__ void scatter_kernel(const int* __restrict__ labels,
                               int* __restrict__ cursor,
                               int* __restrict__ order) {
    int b = blockIdx.x * blockDim.x + threadIdx.x;   // grid == BATCH exactly
    int pos = atomicAdd(&cursor[labels[b]], 1);
    order[pos] = b;
}

// ---------------------------------------------------------------------------
// K6: one wave per G=4 consecutive classes.
//  (a) asm register-pin on all 8 loaded float2 rows between load batch and
//      consume: regalloc MUST keep 16 result VGPRs live -> 8 loads issue,
//      ONE amortized vmcnt wait, 8 consumes. (R4/R5 aliased dests -> WAW
//      waits serialized the loads; VGPR_Count=28 was the tell.)
//  (b) __shfl_xor reduce (6 x ~120cy LDS-pipe hops) replaced by DPP reduce
//      (6 VALU ops, ~30cy chain). Sum lands in lane 63.
// ---------------------------------------------------------------------------
__global__ __launch_bounds__(256, 2)
void main_kernel(const float* __restrict__ features,
                 const float* __restrict__ centers,
                 const int2*  __restrict__ co,
                 const int*   __restrict__ order,
                 float* __restrict__ result,
                 float* __restrict__ out_centers) {
    const int wave = threadIdx.x >> 6;
    const int lane = threadIdx.x & 63;
    const int c0   = (blockIdx.x * 4 + wave) * G;    // grid exact: c0 < C

    const int4 mA = ((const int4*)(co + c0))[0];
    const int4 mB = ((const int4*)(co + c0))[1];
    const int start = __builtin_amdgcn_readfirstlane(mA.x);
    const int n0    = __builtin_amdgcn_readfirstlane(mA.y);
    const int b1    = __builtin_amdgcn_readfirstlane(mA.z);
    const int n1    = __builtin_amdgcn_readfirstlane(mA.w);
    const int b2    = __builtin_amdgcn_readfirstlane(mB.x);
    const int n2    = __builtin_amdgcn_readfirstlane(mB.y);
    const int b3    = __builtin_amdgcn_readfirstlane(mB.z);
    const int n3    = __builtin_amdgcn_readfirstlane(mB.w);
    const int end   = b3 + n3;

    const float2* cp = (const float2*)(centers + (size_t)c0 * D);
    const float2 cv0 = cp[lane];
    const float2 cv1 = cp[lane + 64];
    const float2 cv2 = cp[lane + 128];
    const float2 cv3 = cp[lane + 192];

    float ax0 = 0.f, ay0 = 0.f, ax1 = 0.f, ay1 = 0.f;
    float ax2 = 0.f, ay2 = 0.f, ax3 = 0.f, ay3 = 0.f;

    for (int p0 = start; p0 < end; p0 += 8) {
        // 8 wave-uniform sample indices (scalar loads, clamped tail)
        int bi[8];
        #pragma unroll
        for (int u = 0; u < 8; ++u)
            bi[u] = order[min(p0 + u, end - 1)];
        // 8 independent 512B feature-row loads
        float2 f0 = ((const float2*)(features + (size_t)bi[0] * D))[lane];
        float2 f1 = ((const float2*)(features + (size_t)bi[1] * D))[lane];
        float2 f2 = ((const float2*)(features + (size_t)bi[2] * D))[lane];
        float2 f3 = ((const float2*)(features + (size_t)bi[3] * D))[lane];
        float2 f4 = ((const float2*)(features + (size_t)bi[4] * D))[lane];
        float2 f5 = ((const float2*)(features + (size_t)bi[5] * D))[lane];
        float2 f6 = ((const float2*)(features + (size_t)bi[6] * D))[lane];
        float2 f7 = ((const float2*)(features + (size_t)bi[7] * D))[lane];
        // pin all 16 result registers live: forces batched issue + ONE wait
        asm volatile("" : "+v"(f0.x), "+v"(f0.y), "+v"(f1.x), "+v"(f1.y),
                          "+v"(f2.x), "+v"(f2.y), "+v"(f3.x), "+v"(f3.y),
                          "+v"(f4.x), "+v"(f4.y), "+v"(f5.x), "+v"(f5.y),
                          "+v"(f6.x), "+v"(f6.y), "+v"(f7.x), "+v"(f7.y));
        float2 f[8] = {f0, f1, f2, f3, f4, f5, f6, f7};
        // consume
        #pragma unroll
        for (int u = 0; u < 8; ++u) {
            const int p = p0 + u;                      // wave-uniform
            const float cx = p < b1 ? cv0.x : p < b2 ? cv1.x : p < b3 ? cv2.x : cv3.x;
            const float cy = p < b1 ? cv0.y : p < b2 ? cv1.y : p < b3 ? cv2.y : cv3.y;
            float dx = f[u].x - cx, dy = f[u].y - cy;
            if (p >= end) { dx = 0.f; dy = 0.f; }      // kill tail contribution
            ax0 += (p < b1) ? dx : 0.f;              ay0 += (p < b1) ? dy : 0.f;
            ax1 += (p >= b1 && p < b2) ? dx : 0.f;   ay1 += (p >= b1 && p < b2) ? dy : 0.f;
            ax2 += (p >= b2 && p < b3) ? dx : 0.f;   ay2 += (p >= b2 && p < b3) ? dy : 0.f;
            ax3 += (p >= b3) ? dx : 0.f;             ay3 += (p >= b3) ? dy : 0.f;
            float ss = wave_sum63(dx * dx + dy * dy);  // lane 63 = total
            if (p < end && lane == 63) result[bi[u]] = ss;
        }
    }

    const float i0 = ALPHA_C / (1.0f + (float)n0);
    const float i1 = ALPHA_C / (1.0f + (float)n1);
    const float i2 = ALPHA_C / (1.0f + (float)n2);
    const float i3 = ALPHA_C / (1.0f + (float)n3);
    float2* op = (float2*)(out_centers + (size_t)c0 * D);
    float2 o;
    o.x = cv0.x + ax0 * i0; o.y = cv0.y + ay0 * i0; op[lane]       = o;
    o.x = cv1.x + ax1 * i1; o.y = cv1.y + ay1 * i1; op[lane + 64]  = o;
    o.x = cv2.x + ax2 * i2; o.y = cv2.y + ay2 * i2; op[lane + 128] = o;
    o.x = cv3.x + ax3 * i3; o.y = cv3.y + ay3 * i3; op[lane + 192] = o;
}

// ---------------------------------------------------------------------------
extern "C" void kernel_launch(void* const* d_in, const int* in_sizes, int n_in,
                              void* d_out, int out_size, void* d_ws, size_t ws_size,
                              hipStream_t stream) {
    const float* features = (const float*)d_in[0];
    const int*   labels   = (const int*)d_in[1];
    const float* centers  = (const float*)d_in[2];

    float* result      = (float*)d_out;          // [BATCH]
    float* out_centers = result + BATCH;         // [C_CLASSES * D]

    int*  ws           = (int*)d_ws;             // ~2.1 MB total scratch
    int*  counts       = ws;                     // C
    int2* co           = (int2*)(ws + C_CLASSES);        // 2C ints
    int*  cursor       = ws + 3 * C_CLASSES;     // C
    int*  blockSums    = ws + 4 * C_CLASSES;     // 64
    int*  blockOffsets = blockSums + 64;         // 64
    int*  order        = blockOffsets + 64;      // BATCH

    (void)hipMemsetAsync(counts, 0, C_CLASSES * sizeof(int), stream);

    hist_kernel   <<<BATCH / 256, 256, 0, stream>>>(labels, counts);
    scan1_kernel  <<<NB,          256, 0, stream>>>(counts, co, blockSums);
    scan2_kernel  <<<1,            64, 0, stream>>>(blockSums, blockOffsets);
    addoff_kernel <<<(C_CLASSES + 255) / 256, 256, 0, stream>>>(co, blockOffsets, cursor);
    scatter_kernel<<<BATCH / 256, 256, 0, stream>>>(labels, cursor, order);

    main_kernel   <<<C_CLASSES / (4 * G), 256, 0, stream>>>(
        features, centers, co, order, result, out_centers);
}